// Round 1
// 676.191 us; speedup vs baseline: 1.0275x; 1.0275x over previous
//
#include <hip/hip_runtime.h>
#include <cstdint>
#include <cstddef>

#define BATCH 8
#define SEQ   4096
#define DS    512
#define JPL   8              // states per lane (64 lanes * 8 = 512)
#define BLK   8              // time steps per LDS block
#define NBLK  (SEQ / BLK)    // 512 (even)
#define LN_EPS 1e-5f

typedef float v2f __attribute__((ext_vector_type(2)));
typedef float v4f __attribute__((ext_vector_type(4)));

static __device__ __forceinline__ v2f lo2(v4f x) { return __builtin_shufflevector(x, x, 0, 1); }
static __device__ __forceinline__ v2f hi2(v4f x) { return __builtin_shufflevector(x, x, 2, 3); }

// ---- DPP wave64 reduction: row_shr 1/2/4/8, row_bcast15/31 -> lane 63 ----
template <int CTRL>
__device__ __forceinline__ float dpp_add(float v) {
  int t = __builtin_amdgcn_update_dpp(0, __builtin_bit_cast(int, v), CTRL, 0xF, 0xF, true);
  return v + __builtin_bit_cast(float, t);
}
__device__ __forceinline__ float wave_sum64(float v) {
  v = dpp_add<0x111>(v);
  v = dpp_add<0x112>(v);
  v = dpp_add<0x114>(v);
  v = dpp_add<0x118>(v);
  v = dpp_add<0x142>(v);
  v = dpp_add<0x143>(v);
  return v;  // valid in lane 63
}
__device__ __forceinline__ float bcast63(float v) {
  return __builtin_bit_cast(float, __builtin_amdgcn_readlane(__builtin_bit_cast(int, v), 63));
}

// async HBM -> LDS: per-lane 16B from g, LDS dest = uniform base + lane*16
__device__ __forceinline__ void ld16(const float* g, float* l) {
  __builtin_amdgcn_global_load_lds(
      (const __attribute__((address_space(1))) void*)g,
      (__attribute__((address_space(3))) void*)l, 16, 0, 0);
}

// ---------------- fused scan kernel: 3 waves per batch element ---------------
// wave 0: consumer (recurrence; LDS-only, fully fenced barriers)
// wave 1: DMA x into LDS + reduce previous block's readout + WRITE OUT rows
// wave 2: rg = 1/(1+sigmoid(g)*v) and sum(c*bias*rg) into LDS
__global__ __launch_bounds__(192, 1) void ssm_scan(
    const float* __restrict__ x, const float* __restrict__ vol,
    const float* __restrict__ llr, const float* __restrict__ logb,
    const float* __restrict__ cvec, const float* __restrict__ lstp,
    const float* __restrict__ vgat, const float* __restrict__ lnw,
    const float* __restrict__ lnb, const float* __restrict__ alph,
    const float* __restrict__ logd, float* __restrict__ out)
{
  __shared__ __attribute__((aligned(16))) float X0[4096], X1[4096];  // x tiles
  __shared__ __attribute__((aligned(16))) float R0[4096], R1[4096];  // rg tiles
  __shared__ __attribute__((aligned(16))) float SC0[512], SC1[512];  // per-lane readout partials
  __shared__ __attribute__((aligned(16))) float SB0[512], SB1[512];  // per-lane sum(c*bias*rg)

  const int b    = blockIdx.x;
  const int lane = threadIdx.x & 63;
  const int wid  = threadIdx.x >> 6;

  if (wid == 1) {
    // ===================== DMA + readout-reduce + out-write wave =====================
    const float* xg = x + (size_t)b * SEQ * DS + lane * JPL;
    float* ob = out + (size_t)b * SEQ * DS;
    float al   = 1.0f / (1.0f + expf(-alph[0]));
    float dd   = expf(logd[0]);
    float coef = __builtin_fmaf(1.0f - al, dd, al);  // al + (1-al)*d
    float c1   = 1.0f - al;

    auto dma_blk = [&](int blk, float* Xs) {
#pragma unroll
      for (int u = 0; u < BLK; ++u) {
        const float* row = xg + (size_t)(blk * BLK + u) * DS;
        ld16(row,     Xs + u * 512);         // states [8l..8l+3] -> slots [4l..4l+3]
        ld16(row + 4, Xs + u * 512 + 256);   // states [8l+4..8l+7]
      }
    };
    // reduce SC partials to the readout scalar, write out = coef*x + c1*s.
    // Xs must still hold block `blk` (called BEFORE re-staging that buffer).
    auto out_blk = [&](const float* SCs, const float* Xs, int blk) {
#pragma unroll
      for (int u = 0; u < BLK; ++u) {
        float s  = bcast63(wave_sum64(SCs[u * 64 + lane]));
        float sc = c1 * s;
        v4f xa = *(const v4f*)(Xs + u * 512 + lane * 4);
        v4f xb = *(const v4f*)(Xs + u * 512 + 256 + lane * 4);
        v4f ya = xa * coef + sc;
        v4f yb = xb * coef + sc;
        float* row = ob + (size_t)(blk * BLK + u) * DS + lane * 8;
        *(v4f*)(row)     = ya;
        *(v4f*)(row + 4) = yb;
      }
    };

    dma_blk(0, X0);
    __syncthreads();  // B0
#pragma unroll 1
    for (int i2 = 0; i2 < NBLK; i2 += 2) {
      if (i2 > 0) {
        out_blk(SC1, X1, i2 - 1);                 // X1 still = block i2-1
        // hazard guard: LDS reads of X1 must retire before global_load_lds rewrites it
        asm volatile("s_waitcnt lgkmcnt(0)" ::: "memory");
        __builtin_amdgcn_sched_barrier(0);
      }
      dma_blk(i2 + 1, X1);                        // stage block i2+1
      __syncthreads();
      out_blk(SC0, X0, i2);                       // SC0 sealed; X0 = block i2
      if (i2 + 2 < NBLK) {
        asm volatile("s_waitcnt lgkmcnt(0)" ::: "memory");
        __builtin_amdgcn_sched_barrier(0);
        dma_blk(i2 + 2, X0);                      // stage block i2+2
      }
      __syncthreads();
    }
    out_blk(SC1, X1, NBLK - 1);                   // final block
  } else if (wid == 2) {
    // ===================== gate-reciprocal + c*bias*rg wave =====================
    v2f gate[4];
#pragma unroll
    for (int j = 0; j < JPL; ++j)
      gate[j >> 1][j & 1] = 1.0f / (1.0f + expf(-vgat[lane * JPL + j]));
    v4f cb0, cb1;  // c*bias per state (for readout bias term)
#pragma unroll
    for (int m = 0; m < 4; ++m) {
      int n0 = lane * JPL + m, n1 = lane * JPL + 4 + m;
      cb0[m] = cvec[n0] * lnb[n0];
      cb1[m] = cvec[n1] * lnb[n1];
    }
    const float* vg = vol + (size_t)b * SEQ;

    auto rg_blk = [&](v4f Va, v4f Vb, float* Rs, float* SBs) {
#pragma unroll
      for (int u = 0; u < BLK; ++u) {
        float vt = (u < 4) ? Va[u] : Vb[u - 4];
        v4f r0, r1;
#pragma unroll
        for (int k = 0; k < 4; ++k) {
          v2f den = gate[k] * vt + 1.0f;
          float q0 = __builtin_amdgcn_rcpf(den.x);
          float q1 = __builtin_amdgcn_rcpf(den.y);
          if (k < 2) { r0[2 * k] = q0; r0[2 * k + 1] = q1; }
          else       { r1[2 * (k - 2)] = q0; r1[2 * (k - 2) + 1] = q1; }
        }
        *(v4f*)(Rs + u * 512 + lane * 4)       = r0;
        *(v4f*)(Rs + u * 512 + 256 + lane * 4) = r1;
        v4f md = cb0 * r0;
        md = __builtin_elementwise_fma(cb1, r1, md);
        v2f mh = lo2(md) + hi2(md);
        SBs[u * 64 + lane] = mh.x + mh.y;     // per-lane sum(c*bias*rg)
      }
    };

    v4f V0a = *(const v4f*)(vg + 0), V0b = *(const v4f*)(vg + 4);
    v4f V1a = *(const v4f*)(vg + 8), V1b = *(const v4f*)(vg + 12);
    rg_blk(V0a, V0b, R0, SB0);                   // block 0
    __syncthreads();  // B0
#pragma unroll 1
    for (int i2 = 0; i2 < NBLK; i2 += 2) {
      if (i2 + 2 < NBLK) {
        V0a = *(const v4f*)(vg + (i2 + 2) * BLK);
        V0b = *(const v4f*)(vg + (i2 + 2) * BLK + 4);
      }
      rg_blk(V1a, V1b, R1, SB1);                 // block i2+1
      __syncthreads();
      if (i2 + 3 < NBLK) {
        V1a = *(const v4f*)(vg + (i2 + 3) * BLK);
        V1b = *(const v4f*)(vg + (i2 + 3) * BLK + 4);
      }
      if (i2 + 2 < NBLK) rg_blk(V0a, V0b, R0, SB0);  // block i2+2
      __syncthreads();
    }
  } else {
    // ========================= consumer wave =========================
    // Carried state: hp = a*h_out (pending). hr(t) = hp + bd*x(t).
    // hp' = inv*(aw ⊙ tv) + ab ⊙ rs, with tv = rs ⊙ (hr - mu).
    // Readout: sum(c*h) = inv*sum(cw ⊙ tv) + sum(cb ⊙ rs)  (latter from wave 2)
    v2f bd[4], aw[4], ab[4], cw[4];
#pragma unroll
    for (int j = 0; j < JPL; ++j) {
      int n = lane * JPL + j;
      float lam = -expf(llr[n]);
      float st  = expf(lstp[n]);
      float z   = st * lam;
      float ad  = (2.0f + z) / (2.0f - z);
      float bdv = st * (1.0f + ad) * expf(logb[n]) * 0.5f;
      float wv  = lnw[n], bi = lnb[n], cv = cvec[n];
      bd[j >> 1][j & 1] = bdv;
      aw[j >> 1][j & 1] = ad * wv;
      ab[j >> 1][j & 1] = ad * bi;
      cw[j >> 1][j & 1] = cv * wv;
    }
    v2f hp[4];
#pragma unroll
    for (int k = 0; k < 4; ++k) hp[k] = (v2f){0.0f, 0.0f};

    auto proc_blk = [&](const float* Xs, const float* Rs, const float* SBs, float* SCs) {
#pragma unroll
      for (int u = 0; u < BLK; ++u) {
        v4f xx0 = *(const v4f*)(Xs + u * 512 + lane * 4);
        v4f xx1 = *(const v4f*)(Xs + u * 512 + 256 + lane * 4);
        v4f rr0 = *(const v4f*)(Rs + u * 512 + lane * 4);
        v4f rr1 = *(const v4f*)(Rs + u * 512 + 256 + lane * 4);
        float u3s = SBs[u * 64 + lane];
        v2f xs[4] = {lo2(xx0), hi2(xx0), lo2(xx1), hi2(xx1)};
        v2f rs[4] = {lo2(rr0), hi2(rr0), lo2(rr1), hi2(rr1)};

        v2f hr[4], q[4], abrs[4];
#pragma unroll
        for (int k = 0; k < 4; ++k) {
          hr[k]   = __builtin_elementwise_fma(bd[k], xs[k], hp[k]);  // hr = hp + bd*x
          q[k]    = rs[k] * hr[k];                                   // off inv-path
          abrs[k] = ab[k] * rs[k];                                   // off-chain
        }
        // sum and sum-of-squares trees on hr
        v2f t01 = hr[0] + hr[1], t23 = hr[2] + hr[3];
        v2f tt  = t01 + t23;
        float s1 = tt.x + tt.y;
        v2f m01 = hr[0] * hr[0];
        m01 = __builtin_elementwise_fma(hr[1], hr[1], m01);
        v2f m23 = hr[2] * hr[2];
        m23 = __builtin_elementwise_fma(hr[3], hr[3], m23);
        v2f mm = m01 + m23;
        float s2 = mm.x + mm.y;

        s1 = bcast63(wave_sum64(s1));
        s2 = bcast63(wave_sum64(s2));
        float mu  = s1 * (1.0f / DS);
        float m2e = __builtin_fmaf(s2, 1.0f / DS, LN_EPS);  // eps folded in
        float var = __builtin_fmaf(-mu, mu, m2e);
        float inv = __builtin_amdgcn_rsqf(var);

        v2f muv = {mu, mu}, invv = {inv, inv};
        v2f tv[4];
#pragma unroll
        for (int k = 0; k < 4; ++k)      // starts as soon as mu ready (overlaps rsqrt)
          tv[k] = __builtin_elementwise_fma(-muv, rs[k], q[k]);  // rs*(hr-mu)
#pragma unroll
        for (int k = 0; k < 4; ++k) {    // single FMA level after inv
          v2f sv = aw[k] * tv[k];
          hp[k]  = __builtin_elementwise_fma(invv, sv, abrs[k]);
        }
        // readout partial (off the recurrence path)
        v2f u0 = cw[0] * tv[0];
        u0 = __builtin_elementwise_fma(cw[1], tv[1], u0);
        v2f u2 = cw[2] * tv[2];
        u2 = __builtin_elementwise_fma(cw[3], tv[3], u2);
        v2f uu = u0 + u2;
        float u1s = uu.x + uu.y;
        SCs[u * 64 + lane] = __builtin_fmaf(inv, u1s, u3s);
      }
    };

    __syncthreads();  // B0
#pragma unroll 1
    for (int i2 = 0; i2 < NBLK; i2 += 2) {
      proc_blk(X0, R0, SB0, SC0);
      __syncthreads();
      proc_blk(X1, R1, SB1, SC1);
      __syncthreads();
    }
  }
}

extern "C" void kernel_launch(void* const* d_in, const int* in_sizes, int n_in,
                              void* d_out, int out_size, void* d_ws, size_t ws_size,
                              hipStream_t stream) {
  const float* x    = (const float*)d_in[0];   // [8,4096,512]
  const float* vol  = (const float*)d_in[1];   // [8,4096,1]
  const float* llr  = (const float*)d_in[2];   // [512]
  const float* logb = (const float*)d_in[3];   // [512,1]
  const float* cvec = (const float*)d_in[4];   // [1,512]
  const float* logd = (const float*)d_in[5];   // [1]
  const float* lstp = (const float*)d_in[6];   // [512]
  const float* vgat = (const float*)d_in[7];   // [512]
  const float* alph = (const float*)d_in[8];   // [1]
  const float* lnw  = (const float*)d_in[9];   // [512]
  const float* lnb  = (const float*)d_in[10];  // [512]
  float* outf = (float*)d_out;

  ssm_scan<<<BATCH, 192, 0, stream>>>(x, vol, llr, logb, cvec, lstp,
                                      vgat, lnw, lnb, alph, logd, outf);
}